// Round 23
// baseline (321.548 us; speedup 1.0000x reference)
//
#include <hip/hip_runtime.h>
#include <hip/hip_bf16.h>
#include <stdint.h>

#define SCALE_ 0.125f
#define K_L2E 0.18033688f  // 0.125 * log2(e)

typedef __bf16 bf16x8 __attribute__((ext_vector_type(8)));
typedef float f32x4 __attribute__((ext_vector_type(4)));
typedef unsigned short us8v __attribute__((ext_vector_type(8)));
typedef unsigned int u32x2 __attribute__((ext_vector_type(2)));

__device__ __forceinline__ unsigned short f2bf(float f) {
  unsigned int u = __builtin_bit_cast(unsigned int, f);
  u += 0x7fffu + ((u >> 16) & 1u);
  return (unsigned short)(u >> 16);
}
__device__ __forceinline__ float bf2f(unsigned short h) {
  unsigned int u = ((unsigned int)h) << 16;
  return __builtin_bit_cast(float, u);
}
__device__ __forceinline__ unsigned short f2bf_n(float f) {  // native cvt (RNE)
  __bf16 b = (__bf16)f;
  return __builtin_bit_cast(unsigned short, b);
}
__device__ __forceinline__ unsigned packbf(float lo, float hi) {
  return (unsigned)f2bf_n(lo) | ((unsigned)f2bf_n(hi) << 16);
}
__device__ __forceinline__ float exp2_fast(float x) {
  return __builtin_amdgcn_exp2f(x);  // v_exp_f32 (base-2)
}
__device__ __forceinline__ f32x4 mfma16(bf16x8 a, bf16x8 b, f32x4 c) {
  return __builtin_amdgcn_mfma_f32_16x16x32_bf16(a, b, c, 0, 0, 0);
}
__device__ __forceinline__ f32x4 max4(f32x4 a, f32x4 b) {
  f32x4 r;
  r[0] = fmaxf(a[0], b[0]); r[1] = fmaxf(a[1], b[1]);
  r[2] = fmaxf(a[2], b[2]); r[3] = fmaxf(a[3], b[3]);
  return r;
}
// async global->LDS, 16B per lane. LDS dest wave-uniform base + lane*16.
__device__ __forceinline__ void gl2lds16(const unsigned short* g, unsigned short* l) {
  __builtin_amdgcn_global_load_lds(
      (const __attribute__((address_space(1))) unsigned int*)g,
      (__attribute__((address_space(3))) unsigned int*)l, 16, 0, 0);
}

// ---------------- fp32 -> bf16 convert: hidden + all 4 weights, ONE launch ----
__global__ __launch_bounds__(256) void cvt5_kernel(
    const float* __restrict__ sh, const float* __restrict__ s0,
    const float* __restrict__ s1, const float* __restrict__ s2,
    const float* __restrict__ s3, unsigned short* __restrict__ dh,
    unsigned short* __restrict__ d0, unsigned short* __restrict__ d1,
    unsigned short* __restrict__ d2, unsigned short* __restrict__ d3) {
  const int idx = blockIdx.x * 256 + threadIdx.x;
  const float* src;
  unsigned short* dst;
  size_t off;
  if (idx < 2097152) {
    src = sh; dst = dh; off = (size_t)idx;
  } else {
    const int j = idx - 2097152;
    const int which = j >> 17;
    off = (size_t)(j & 131071);
    src = (which == 0) ? s0 : (which == 1) ? s1 : (which == 2) ? s2 : s3;
    dst = (which == 0) ? d0 : (which == 1) ? d1 : (which == 2) ? d2 : d3;
  }
  us8v o;
#pragma unroll
  for (int e = 0; e < 8; ++e) o[e] = f2bf(src[off * 8 + e]);
  *(us8v*)(dst + off * 8) = o;
}

// ---------------- GEMM: C = A(Mx1024) @ W^T ----------------
// BK=64, row-XOR-swizzled LDS; pre-swizzled global source + linear LDS dest.
template <int MODE>
__global__ __launch_bounds__(256, 2) void gemm_kernel(
    const unsigned short* __restrict__ A, const unsigned short* __restrict__ W0,
    const unsigned short* __restrict__ W1, const unsigned short* __restrict__ W2,
    unsigned short* __restrict__ Qb, unsigned short* __restrict__ Kb,
    unsigned short* __restrict__ VT, const float* __restrict__ cosT,
    const float* __restrict__ sinT, float* __restrict__ Out) {
  __shared__ unsigned short As[128 * 64];
  __shared__ unsigned short Bs[128 * 64];
  const int tid = threadIdx.x;
  const int lane = tid & 63, wv = tid >> 6;
  const int lr = lane & 15, lg = lane >> 4;
  const int wr = wv >> 1, wc = wv & 1;
  const int tm = blockIdx.x * 16 + (blockIdx.y >> 3);  // XCD-chunked
  const int tn = blockIdx.y & 7;
  const int z = blockIdx.z;
  const unsigned short* Wp = (MODE == 1) ? W0 : (z == 0 ? W0 : (z == 1 ? W1 : W2));
  const unsigned short* Ab = A + (size_t)tm * 128 * 1024;
  const unsigned short* Wb = Wp + (size_t)tn * 128 * 1024;

  f32x4 zero = {0.f, 0.f, 0.f, 0.f};
  f32x4 acc[4][4];
#pragma unroll
  for (int i = 0; i < 4; ++i)
#pragma unroll
    for (int j = 0; j < 4; ++j) acc[i][j] = zero;

  const int sw = lr & 7;  // read-side row-XOR (row&7 == lr&7 for our rows)

  for (int ks = 0; ks < 16; ++ks) {
    const int k0 = ks * 64;
    __syncthreads();
#pragma unroll
    for (int i = 0; i < 4; ++i) {
      const int row = i * 32 + (tid >> 3);
      const int src8 = (tid & 7) ^ (row & 7);  // pre-swizzled global source
      gl2lds16(Ab + (size_t)row * 1024 + k0 + src8 * 8,
               As + row * 64 + (tid & 7) * 8);
      gl2lds16(Wb + (size_t)row * 1024 + k0 + src8 * 8,
               Bs + row * 64 + (tid & 7) * 8);
    }
    __syncthreads();
#pragma unroll
    for (int kk = 0; kk < 2; ++kk) {
      bf16x8 av[4], bv[4];
#pragma unroll
      for (int mt = 0; mt < 4; ++mt)
        av[mt] = *(const bf16x8*)(As + (wr * 64 + mt * 16 + lr) * 64 +
                                  (((kk * 4 + lg) ^ sw) * 8));
#pragma unroll
      for (int nt = 0; nt < 4; ++nt)
        bv[nt] = *(const bf16x8*)(Bs + (wc * 64 + nt * 16 + lr) * 64 +
                                  (((kk * 4 + lg) ^ sw) * 8));
      __builtin_amdgcn_s_setprio(1);
#pragma unroll
      for (int mt = 0; mt < 4; ++mt)
#pragma unroll
        for (int nt = 0; nt < 4; ++nt)
          acc[mt][nt] = mfma16(av[mt], bv[nt], acc[mt][nt]);
      __builtin_amdgcn_s_setprio(0);
    }
  }

  if constexpr (MODE == 0) {
    if (z < 2) {  // Q/K: RoPE + row-major (B,H,S,D)
      unsigned short* Dst = (z == 0) ? Qb : Kb;
#pragma unroll
      for (int mt = 0; mt < 4; ++mt) {
#pragma unroll
        for (int r = 0; r < 4; ++r) {
          const int m = tm * 128 + wr * 64 + mt * 16 + lg * 4 + r;
          const int b = m >> 12, s = m & 4095;
#pragma unroll
          for (int nt = 0; nt < 4; ++nt) {
            const int n = tn * 128 + wc * 64 + nt * 16 + lr;
            const int h = n >> 6, d = n & 63;
            float v = acc[mt][nt][r];
            const float cs = cosT[s * 64 + d];
            const float sn = sinT[s * 64 + d];
            const float pv = acc[mt][nt ^ 2][r];
            v = v * cs + ((nt < 2) ? -pv : pv) * sn;
            Dst[((size_t)(b * 16 + h) * 4096 + s) * 64 + d] = f2bf_n(v);
          }
        }
      }
    } else {  // V: transposed (B,H,D,S), b64 writes (r-consecutive s)
#pragma unroll
      for (int mt = 0; mt < 4; ++mt) {
        const int m0 = tm * 128 + wr * 64 + mt * 16 + lg * 4;
        const int b = m0 >> 12, s0 = m0 & 4095;
#pragma unroll
        for (int nt = 0; nt < 4; ++nt) {
          const int n = tn * 128 + wc * 64 + nt * 16 + lr;
          const int h = n >> 6, d = n & 63;
          u32x2 pw;
          pw[0] = packbf(acc[mt][nt][0], acc[mt][nt][1]);
          pw[1] = packbf(acc[mt][nt][2], acc[mt][nt][3]);
          *(u32x2*)(VT + ((size_t)(b * 16 + h) * 64 + d) * 4096 + s0) = pw;
        }
      }
    }
  } else {
#pragma unroll
    for (int mt = 0; mt < 4; ++mt) {
#pragma unroll
      for (int r = 0; r < 4; ++r) {
        const int m = tm * 128 + wr * 64 + mt * 16 + lg * 4 + r;
#pragma unroll
        for (int nt = 0; nt < 4; ++nt) {
          const int n = tn * 128 + wc * 64 + nt * 16 + lr;
          Out[(size_t)m * 1024 + n] = acc[mt][nt][r];
        }
      }
    }
  }
}

// ---------------- RFA prep: beta/gamma softmax over 128 chunk positions ----------------
__global__ __launch_bounds__(128) void prep_kernel(
    const unsigned short* __restrict__ Kb, const unsigned short* __restrict__ VT,
    const float* __restrict__ mu, const float* __restrict__ phi,
    unsigned short* __restrict__ rfaK, unsigned short* __restrict__ rfaVT) {
  __shared__ float kc[128][65];
  __shared__ float betaS[128], gammaS[128];
  __shared__ float red[8];
  const int tid = threadIdx.x, lane = tid & 63, wid = tid >> 6;
  const int bh = blockIdx.x >> 5, c = blockIdx.x & 31;
  const int h = bh & 15;
  const size_t rowbase = ((size_t)bh * 4096 + c * 128 + tid) * 64;

  float nn = 0.f, dmu = 0.f, dphi = 0.f;
#pragma unroll
  for (int d8 = 0; d8 < 8; ++d8) {
    us8v kv = *(const us8v*)(Kb + rowbase + d8 * 8);
#pragma unroll
    for (int e = 0; e < 8; ++e) {
      const int d = d8 * 8 + e;
      const float kf = bf2f(kv[e]);
      kc[tid][d] = kf;
      nn += kf * kf;
      dmu += kf * mu[h * 64 + d];
      dphi += kf * phi[h * 64 + d];
    }
  }
  const float lb = SCALE_ * dmu - 0.5f * SCALE_ * nn;
  const float lgm = SCALE_ * dphi - 0.5f * SCALE_ * nn;
  float mb = lb, mg = lgm;
  for (int off = 1; off < 64; off <<= 1) {
    mb = fmaxf(mb, __shfl_xor(mb, off));
    mg = fmaxf(mg, __shfl_xor(mg, off));
  }
  if (lane == 0) { red[wid * 2] = mb; red[wid * 2 + 1] = mg; }
  __syncthreads();
  mb = fmaxf(red[0], red[2]);
  mg = fmaxf(red[1], red[3]);
  const float eb = __expf(lb - mb), eg = __expf(lgm - mg);
  float sb = eb, sg = eg;
  for (int off = 1; off < 64; off <<= 1) {
    sb += __shfl_xor(sb, off);
    sg += __shfl_xor(sg, off);
  }
  if (lane == 0) { red[4 + wid * 2] = sb; red[4 + wid * 2 + 1] = sg; }
  betaS[tid] = eb;
  gammaS[tid] = eg;
  __syncthreads();
  sb = red[4] + red[6];
  sg = red[5] + red[7];

  if (tid < 64) {
    float a = 0.f;
    for (int j = 0; j < 128; ++j) a += betaS[j] * kc[j][tid];
    rfaK[((size_t)bh * 32 + c) * 64 + tid] = f2bf(a / sb);
    const unsigned short* vrow = VT + ((size_t)bh * 64 + tid) * 4096 + c * 128;
    float av = 0.f;
#pragma unroll
    for (int j8 = 0; j8 < 16; ++j8) {
      us8v vv = *(const us8v*)(vrow + j8 * 8);
#pragma unroll
      for (int e = 0; e < 8; ++e) av += gammaS[j8 * 8 + e] * bf2f(vv[e]);
    }
    rfaVT[((size_t)bh * 64 + tid) * 32 + c] = f2bf(av / sg);
  }
}

// ---------------- dual-fragment attention tile, shared P buffer ----------------
// stB is packed to bf16 (pbB, 16 regs) immediately in softmax-B, halving the
// live range carried across PV-A (was 32 f32 regs -> ~110MB/dispatch spill).
template <int NCT, bool HASA, bool MASKA, bool MASKB, bool CH>
__device__ __forceinline__ void attn_tile2(
    const unsigned short* __restrict__ klds, const unsigned short* __restrict__ vsrc,
    int t, int w, int qrA, int qrB, int lr, int lg, const bf16x8* qaA,
    const bf16x8* qaB, f32x4* oA, f32x4* oB, float& mA, float& lA, float& mB,
    float& lB, unsigned short (*__restrict__ PtW)[128]) {
  constexpr int VSTRIDE = CH ? 32 : 4096;
  constexpr int NKS = CH ? 1 : 4;
  const int sw = lr & 7;
  // --- V^T fragment loads up front (latency hides under QK^T + softmax) ---
  bf16x8 vf[NKS * 4];
#pragma unroll
  for (int ks = 0; ks < NKS; ++ks)
#pragma unroll
    for (int dt = 0; dt < 4; ++dt)
      vf[ks * 4 + dt] =
          *(const bf16x8*)(vsrc + (size_t)(dt * 16) * VSTRIDE + ks * 32);
  // --- QK^T from LDS K (swizzled read; row&7 == lr&7) ---
  f32x4 stA[NCT], stB[NCT];
#pragma unroll
  for (int ct = 0; ct < NCT; ++ct) {
    bf16x8 b0 = *(const bf16x8*)(klds + (ct * 16 + lr) * 64 + ((lg ^ sw) * 8));
    bf16x8 b1 = *(const bf16x8*)(klds + (ct * 16 + lr) * 64 + (((4 + lg) ^ sw) * 8));
    f32x4 sb_ = {0.f, 0.f, 0.f, 0.f};
    sb_ = mfma16(b0, qaB[0], sb_);
    sb_ = mfma16(b1, qaB[1], sb_);
    f32x4 sa_ = {0.f, 0.f, 0.f, 0.f};
    if constexpr (HASA) {
      sa_ = mfma16(b0, qaA[0], sa_);
      sa_ = mfma16(b1, qaA[1], sa_);
    }
#pragma unroll
    for (int r = 0; r < 4; ++r) {
      const int kidx = ct * 16 + lg * 4 + r;
      float svb = sb_[r] * K_L2E;
      if constexpr (CH) {
        if (kidx >= 4 * w) svb = -1e30f;
      } else if constexpr (MASKB) {
        if (t * 128 + kidx > qrB) svb = -1e30f;
      }
      sb_[r] = svb;
      if constexpr (HASA) {
        float sva = sa_[r] * K_L2E;
        if constexpr (CH) {
          if (kidx >= 4 * w) sva = -1e30f;
        } else if constexpr (MASKA) {
          if (t * 128 + kidx > qrA) sva = -1e30f;
        }
        sa_[r] = sva;
      }
    }
    stB[ct] = sb_;
    if constexpr (HASA) stA[ct] = sa_;
  }
  // --- softmax A and B (independent chains, compiler interleaves) ---
  if constexpr (HASA) {
    f32x4 m4 = stA[0];
#pragma unroll
    for (int ct = 1; ct < NCT; ++ct) m4 = max4(m4, stA[ct]);
    float rm = fmaxf(fmaxf(m4[0], m4[1]), fmaxf(m4[2], m4[3]));
    rm = fmaxf(rm, __shfl_xor(rm, 16));
    rm = fmaxf(rm, __shfl_xor(rm, 32));
    const float mn = fmaxf(mA, rm);
    const float a = exp2_fast(mA - mn);
    f32x4 s4 = {0.f, 0.f, 0.f, 0.f};
#pragma unroll
    for (int ct = 0; ct < NCT; ++ct) {
#pragma unroll
      for (int r = 0; r < 4; ++r) stA[ct][r] = exp2_fast(stA[ct][r] - mn);
      s4 += stA[ct];
    }
    float rs = (s4[0] + s4[1]) + (s4[2] + s4[3]);
    rs += __shfl_xor(rs, 16);
    rs += __shfl_xor(rs, 32);
    lA = lA * a + rs;
    mA = mn;
#pragma unroll
    for (int dt = 0; dt < 4; ++dt)
#pragma unroll
      for (int r = 0; r < 4; ++r) oA[dt][r] *= a;
  }
  // softmax B: pack P_B to bf16 immediately (stB dies here; pbB = 16 regs)
  u32x2 pbB[NCT];
  {
    f32x4 m4 = stB[0];
#pragma unroll
    for (int ct = 1; ct < NCT; ++ct) m4 = max4(m4, stB[ct]);
    float rm = fmaxf(fmaxf(m4[0], m4[1]), fmaxf(m4[2], m4[3]));
    rm = fmaxf(rm, __shfl_xor(rm, 16));
    rm = fmaxf(rm, __shfl_xor(rm, 32));
    const float mn = fmaxf(mB, rm);
    const float a = exp2_fast(mB - mn);
    f32x4 s4 = {0.f, 0.f, 0.f, 0.f};
#pragma unroll
    for (int ct = 0; ct < NCT; ++ct) {
#pragma unroll
      for (int r = 0; r < 4; ++r) stB[ct][r] = exp2_fast(stB[ct][r] - mn);
      s4 += stB[ct];
      pbB[ct][0] = packbf(stB[ct][0], stB[ct][1]);
      pbB[ct][1] = packbf(stB[ct][2], stB[ct][3]);
    }
    float rs = (s4[0] + s4[1]) + (s4[2] + s4[3]);
    rs += __shfl_xor(rs, 16);
    rs += __shfl_xor(rs, 32);
    lB = lB * a + rs;
    mB = mn;
#pragma unroll
    for (int dt = 0; dt < 4; ++dt)
#pragma unroll
      for (int r = 0; r < 4; ++r) oB[dt][r] *= a;
  }
  // --- PV-A through shared P buffer ---
  if constexpr (HASA) {
#pragma unroll
    for (int ct = 0; ct < NCT; ++ct) {
      u32x2 pw;
      pw[0] = packbf(stA[ct][0], stA[ct][1]);
      pw[1] = packbf(stA[ct][2], stA[ct][3]);
      *(u32x2*)&PtW[lr][((2 * ct + (lg >> 1)) ^ sw) * 8 + (lg & 1) * 4] = pw;
    }
    asm volatile("s_waitcnt lgkmcnt(0)" ::: "memory");
    __builtin_amdgcn_s_setprio(1);
#pragma unroll
    for (int ks = 0; ks < NKS; ++ks) {
      bf16x8 pfA = *(const bf16x8*)&PtW[lr][((ks * 4 + lg) ^ sw) * 8];
#pragma unroll
      for (int dt = 0; dt < 4; ++dt)
        oA[dt] = mfma16(vf[ks * 4 + dt], pfA, oA[dt]);
    }
    __builtin_amdgcn_s_setprio(0);
  }
  // --- PV-B (PB writes queue after PA reads: in-wave DS order -> WAR safe) ---
#pragma unroll
  for (int ct = 0; ct < NCT; ++ct)
    *(u32x2*)&PtW[lr][((2 * ct + (lg >> 1)) ^ sw) * 8 + (lg & 1) * 4] = pbB[ct];
  asm volatile("s_waitcnt lgkmcnt(0)" ::: "memory");
  __builtin_amdgcn_s_setprio(1);
#pragma unroll
  for (int ks = 0; ks < NKS; ++ks) {
    bf16x8 pfB = *(const bf16x8*)&PtW[lr][((ks * 4 + lg) ^ sw) * 8];
#pragma unroll
    for (int dt = 0; dt < 4; ++dt)
      oB[dt] = mfma16(vf[ks * 4 + dt], pfB, oB[dt]);
  }
  __builtin_amdgcn_s_setprio(0);
}

// 2048 blocks; wave carries q-fragments {p, 7-p} through ONE k-loop. K tiles
// staged via global_load_lds one tile ahead (double-buffered, swizzled source).
// launch_bounds (256,2): measured-best config.
__global__ __launch_bounds__(256, 2) void attn_kernel(
    const unsigned short* __restrict__ Qb, const unsigned short* __restrict__ Kb,
    const unsigned short* __restrict__ VT, const unsigned short* __restrict__ rfaK,
    const unsigned short* __restrict__ rfaVT, unsigned short* __restrict__ AO) {
  __shared__ unsigned short Klds[2][128][64];  // 32 KB, linear; holds swizzled K
  __shared__ unsigned short Pt[4][16][128];    // 16 KB, shared A/B P per wave
  const int tid = threadIdx.x, lane = tid & 63, wv = tid >> 6;
  const int lr = lane & 15, lg = lane >> 4;
  // XCD-aware swizzle (bijective: 2048 = 8 * 256)
  const int orig = (blockIdx.x & 7) * 256 + (blockIdx.x >> 3);
  const int p = orig & 3, w = (orig >> 2) & 7, bh = orig >> 5;
  const size_t headbase = (size_t)bh * 4096 * 64;
  const int b = bh >> 4, h = bh & 15;

  const int qtA = p, qtB = 7 - p;
  const int qrA = qtA * 64 + wv * 16 + lr;
  const int qrB = qtB * 64 + wv * 16 + lr;

  bf16x8 qaA[2], qaB[2];
  {
    const size_t qoffA = headbase + (size_t)(w * 512 + qrA) * 64;
    qaA[0] = *(const bf16x8*)(Qb + qoffA + lg * 8);
    qaA[1] = *(const bf16x8*)(Qb + qoffA + 32 + lg * 8);
    const size_t qoffB = headbase + (size_t)(w * 512 + qrB) * 64;
    qaB[0] = *(const bf16x8*)(Qb + qoffB + lg * 8);
    qaB[1] = *(const bf16x8*)(Qb + qoffB + 32 + lg * 8);
  }
  f32x4 oA[4], oB[4];
  float mA = -INFINITY, lA = 0.f, mB = -INFINITY, lB = 0.f;
  {
    f32x4 zero = {0.f, 0.f, 0.f, 0.f};
#pragma unroll
    for (int dt = 0; dt < 4; ++dt) { oA[dt] = zero; oB[dt] = zero; }
  }

  unsigned short(*PtW)[128] = Pt[wv];
  const unsigned short* vwin =
      VT + ((size_t)bh * 64 + lr) * 4096 + w * 512 + lg * 8;
  const unsigned short* vchk = rfaVT + ((size_t)bh * 64 + lr) * 32 + lg * 8;
  const unsigned short* kwin = Kb + headbase + (size_t)(w * 512) * 64;
  const unsigned short* kchk = rfaK + (size_t)bh * 32 * 64;

  auto stage_win = [&](const unsigned short* src, int buf) {
#pragma unroll
    for (int i = 0; i < 4; ++i) {
      const int row = wv * 32 + i * 8 + (lane >> 3);
      gl2lds16(src + row * 64 + (((lane & 7) ^ (row & 7)) * 8),
               &Klds[buf][wv * 32 + i * 8][0] + lane * 8);
    }
  };
  auto stage_chk = [&](int buf) {
    const int row = wv * 8 + (lane >> 3);
    gl2lds16(kchk + row * 64 + (((lane & 7) ^ (row & 7)) * 8),
             &Klds[buf][wv * 8][0] + lane * 8);
  };

  const int nktA = (qtA + 2) >> 1;  // 1,1,2,2
  const int nktB = (qtB + 2) >> 1;  // 4,4,3,3  (always > nktA)

  stage_win(kwin, 0);  // prologue: K(0) DMA in flight

  for (int t = 0; t < nktB; ++t) {
    __syncthreads();  // drains K(t) DMA; all waves done reading buf[(t+1)&1]
    if (t + 1 < nktB) {
      stage_win(kwin + (size_t)(t + 1) * 128 * 64, (t + 1) & 1);
    } else if (w > 0) {
      stage_chk((t + 1) & 1);
    }
    const unsigned short* klds = &Klds[t & 1][0][0];
    const unsigned short* vsrc = vwin + t * 128;
    if (t < nktA) {
      if (t == nktA - 1) {
        attn_tile2<8, true, true, false, false>(klds, vsrc, t, w, qrA, qrB, lr,
                                                lg, qaA, qaB, oA, oB, mA, lA, mB,
                                                lB, PtW);
      } else {
        attn_tile2<8, true, false, false, false>(klds, vsrc, t, w, qrA, qrB, lr,
                                                 lg, qaA, qaB, oA, oB, mA, lA,
                                                 mB, lB, PtW);
      }
    } else {
      if (t == nktB - 1) {
        attn_tile2<8, false, false, true, false>(klds, vsrc, t, w, qrA, qrB, lr,
                                                 lg, qaA, qaB, oA, oB, mA, lA,
                                                 mB, lB, PtW);
      } else {
        attn_tile2<8, false, false, false, false>(klds, vsrc, t, w, qrA, qrB, lr,
                                                  lg, qaA, qaB, oA, oB, mA, lA,
                                                  mB, lB, PtW);
      }
    }
  }
  if (w > 0) {
    __syncthreads();  // chunk-K DMA complete
    attn_tile2<2, true, false, false, true>(&Klds[nktB & 1][0][0], vchk, 0, w,
                                            qrA, qrB, lr, lg, qaA, qaB, oA, oB,
                                            mA, lA, mB, lB, PtW);
  }

  // --- epilogues: A then B through the shared P buffer ---
  const int q2 = lane >> 2, db = lane & 3;
  const int sw = lr & 7;
  const int swq = q2 & 7;
  {
    const float inv = 1.0f / lA;
#pragma unroll
    for (int dt = 0; dt < 4; ++dt) {
      u32x2 pw;
      pw[0] = packbf(oA[dt][0] * inv, oA[dt][1] * inv);
      pw[1] = packbf(oA[dt][2] * inv, oA[dt][3] * inv);
      *(u32x2*)&PtW[lr][((2 * dt + (lg >> 1)) ^ sw) * 8 + (lg & 1) * 4] = pw;
    }
    asm volatile("s_waitcnt lgkmcnt(0)" ::: "memory");
    us8v a0 = *(const us8v*)&PtW[q2][((2 * db) ^ swq) * 8];
    us8v a1 = *(const us8v*)&PtW[q2][((2 * db + 1) ^ swq) * 8];
    const int sA = w * 512 + qtA * 64 + wv * 16 + q2;
    unsigned short* dstA = AO + ((size_t)(b * 4096 + sA)) * 1024 + h * 64 + db * 16;
    *(us8v*)dstA = a0;
    *(us8v*)(dstA + 8) = a1;
  }
  {
    const float invb = 1.0f / lB;
#pragma unroll
    for (int dt = 0; dt < 4; ++dt) {
      u32x2 pw;
      pw[0] = packbf(oB[dt][0] * invb, oB[dt][1] * invb);
      pw[1] = packbf(oB[dt][2] * invb, oB[dt][3] * invb);
      *(u32x2*)&PtW[lr][((2 * dt + (lg >> 1)) ^ sw) * 8 + (lg & 1) * 4] = pw;
    }
    asm volatile("s_waitcnt lgkmcnt(0)" ::: "memory");
    us8v b0 = *(const us8v*)&PtW[q2][((2 * db) ^ swq) * 8];
    us8v b1 = *(const us8v*)&PtW[q2][((2 * db + 1) ^ swq) * 8];
    const int sB = w * 512 + qtB * 64 + wv * 16 + q2;
    unsigned short* dstB = AO + ((size_t)(b * 4096 + sB)) * 1024 + h * 64 + db * 16;
    *(us8v*)dstB = b0;
    *(us8v*)(dstB + 8) = b1;
  }
}

// ---------------- host launch ----------------
extern "C" void kernel_launch(void* const* d_in, const int* in_sizes, int n_in,
                              void* d_out, int out_size, void* d_ws, size_t ws_size,
                              hipStream_t stream) {
  const float* hidden = (const float*)d_in[0];
  const float* Wq = (const float*)d_in[1];
  const float* Wk = (const float*)d_in[2];
  const float* Wv = (const float*)d_in[3];
  const float* Wo = (const float*)d_in[4];
  const float* mu = (const float*)d_in[5];
  const float* phi = (const float*)d_in[6];
  const float* cosT = (const float*)d_in[7];
  const float* sinT = (const float*)d_in[8];
  float* out = (float*)d_out;

  char* ws = (char*)d_ws;
  unsigned short* hid_bf = (unsigned short*)(ws);
  unsigned short* wq_bf = (unsigned short*)(ws + 33554432);
  unsigned short* wk_bf = (unsigned short*)(ws + 35651584);
  unsigned short* wv_bf = (unsigned short*)(ws + 37748736);
  unsigned short* wo_bf = (unsigned short*)(ws + 39845888);
  unsigned short* Qb = (unsigned short*)(ws + 41943040);
  unsigned short* Kb = (unsigned short*)(ws + 75497472);
  unsigned short* VT = (unsigned short*)(ws + 109051904);   // (B,H,D,S) bf16
  unsigned short* ao_bf = (unsigned short*)(ws + 142606336);
  unsigned short* rfaK = (unsigned short*)(ws + 176160768);
  unsigned short* rfaVT = (unsigned short*)(ws + 176422912);  // [bh][d][c]

  // hidden + 4 weights in ONE launch: 2097152 + 4*131072 = 2621440 groups
  cvt5_kernel<<<10240, 256, 0, stream>>>(hidden, Wq, Wk, Wv, Wo, hid_bf, wq_bf,
                                         wk_bf, wv_bf, wo_bf);

  gemm_kernel<0><<<dim3(8, 128, 3), 256, 0, stream>>>(
      hid_bf, wq_bf, wk_bf, wv_bf, Qb, Kb, VT, cosT, sinT, nullptr);

  prep_kernel<<<2048, 128, 0, stream>>>(Kb, VT, mu, phi, rfaK, rfaVT);

  attn_kernel<<<2048, 256, 0, stream>>>(Qb, Kb, VT, rfaK, rfaVT, ao_bf);

  gemm_kernel<1><<<dim3(8, 128, 1), 256, 0, stream>>>(
      ao_bf, wo_bf, nullptr, nullptr, nullptr, nullptr, nullptr, nullptr, nullptr,
      out);
}

// Round 24
// 306.235 us; speedup vs baseline: 1.0500x; 1.0500x over previous
//
#include <hip/hip_runtime.h>
#include <hip/hip_bf16.h>
#include <stdint.h>

#define SCALE_ 0.125f
#define K_L2E 0.18033688f  // 0.125 * log2(e)

typedef __bf16 bf16x8 __attribute__((ext_vector_type(8)));
typedef float f32x4 __attribute__((ext_vector_type(4)));
typedef unsigned short us8v __attribute__((ext_vector_type(8)));
typedef unsigned int u32x2 __attribute__((ext_vector_type(2)));

__device__ __forceinline__ unsigned short f2bf(float f) {
  unsigned int u = __builtin_bit_cast(unsigned int, f);
  u += 0x7fffu + ((u >> 16) & 1u);
  return (unsigned short)(u >> 16);
}
__device__ __forceinline__ float bf2f(unsigned short h) {
  unsigned int u = ((unsigned int)h) << 16;
  return __builtin_bit_cast(float, u);
}
__device__ __forceinline__ unsigned short f2bf_n(float f) {  // native cvt (RNE)
  __bf16 b = (__bf16)f;
  return __builtin_bit_cast(unsigned short, b);
}
__device__ __forceinline__ unsigned packbf(float lo, float hi) {
  return (unsigned)f2bf_n(lo) | ((unsigned)f2bf_n(hi) << 16);
}
__device__ __forceinline__ float exp2_fast(float x) {
  return __builtin_amdgcn_exp2f(x);  // v_exp_f32 (base-2)
}
__device__ __forceinline__ f32x4 mfma16(bf16x8 a, bf16x8 b, f32x4 c) {
  return __builtin_amdgcn_mfma_f32_16x16x32_bf16(a, b, c, 0, 0, 0);
}
__device__ __forceinline__ f32x4 max4(f32x4 a, f32x4 b) {
  f32x4 r;
  r[0] = fmaxf(a[0], b[0]); r[1] = fmaxf(a[1], b[1]);
  r[2] = fmaxf(a[2], b[2]); r[3] = fmaxf(a[3], b[3]);
  return r;
}
// async global->LDS, 16B per lane. LDS dest wave-uniform base + lane*16.
__device__ __forceinline__ void gl2lds16(const unsigned short* g, unsigned short* l) {
  __builtin_amdgcn_global_load_lds(
      (const __attribute__((address_space(1))) unsigned int*)g,
      (__attribute__((address_space(3))) unsigned int*)l, 16, 0, 0);
}

// ---------------- fp32 -> bf16 convert: hidden + all 4 weights, ONE launch ----
// idx < 2^21: hidden (2097152 groups of 8). Else weight j = idx - 2^21,
// which = j>>17 (4 x 131072 groups).
__global__ __launch_bounds__(256) void cvt5_kernel(
    const float* __restrict__ sh, const float* __restrict__ s0,
    const float* __restrict__ s1, const float* __restrict__ s2,
    const float* __restrict__ s3, unsigned short* __restrict__ dh,
    unsigned short* __restrict__ d0, unsigned short* __restrict__ d1,
    unsigned short* __restrict__ d2, unsigned short* __restrict__ d3) {
  const int idx = blockIdx.x * 256 + threadIdx.x;
  const float* src;
  unsigned short* dst;
  size_t off;
  if (idx < 2097152) {
    src = sh; dst = dh; off = (size_t)idx;
  } else {
    const int j = idx - 2097152;
    const int which = j >> 17;
    off = (size_t)(j & 131071);
    src = (which == 0) ? s0 : (which == 1) ? s1 : (which == 2) ? s2 : s3;
    dst = (which == 0) ? d0 : (which == 1) ? d1 : (which == 2) ? d2 : d3;
  }
  us8v o;
#pragma unroll
  for (int e = 0; e < 8; ++e) o[e] = f2bf(src[off * 8 + e]);
  *(us8v*)(dst + off * 8) = o;
}

// ---------------- GEMM: C = A(Mx1024) @ W^T ----------------
// BK=64, row-XOR-swizzled LDS; pre-swizzled global source + linear LDS dest.
template <int MODE>
__global__ __launch_bounds__(256, 2) void gemm_kernel(
    const unsigned short* __restrict__ A, const unsigned short* __restrict__ W0,
    const unsigned short* __restrict__ W1, const unsigned short* __restrict__ W2,
    unsigned short* __restrict__ Qb, unsigned short* __restrict__ Kb,
    unsigned short* __restrict__ VT, const float* __restrict__ cosT,
    const float* __restrict__ sinT, float* __restrict__ Out) {
  __shared__ unsigned short As[128 * 64];
  __shared__ unsigned short Bs[128 * 64];
  const int tid = threadIdx.x;
  const int lane = tid & 63, wv = tid >> 6;
  const int lr = lane & 15, lg = lane >> 4;
  const int wr = wv >> 1, wc = wv & 1;
  const int tm = blockIdx.x * 16 + (blockIdx.y >> 3);  // XCD-chunked
  const int tn = blockIdx.y & 7;
  const int z = blockIdx.z;
  const unsigned short* Wp = (MODE == 1) ? W0 : (z == 0 ? W0 : (z == 1 ? W1 : W2));
  const unsigned short* Ab = A + (size_t)tm * 128 * 1024;
  const unsigned short* Wb = Wp + (size_t)tn * 128 * 1024;

  f32x4 zero = {0.f, 0.f, 0.f, 0.f};
  f32x4 acc[4][4];
#pragma unroll
  for (int i = 0; i < 4; ++i)
#pragma unroll
    for (int j = 0; j < 4; ++j) acc[i][j] = zero;

  const int sw = lr & 7;  // read-side row-XOR (row&7 == lr&7 for our rows)

  for (int ks = 0; ks < 16; ++ks) {
    const int k0 = ks * 64;
    __syncthreads();
#pragma unroll
    for (int i = 0; i < 4; ++i) {
      const int row = i * 32 + (tid >> 3);
      const int src8 = (tid & 7) ^ (row & 7);  // pre-swizzled global source
      gl2lds16(Ab + (size_t)row * 1024 + k0 + src8 * 8,
               As + row * 64 + (tid & 7) * 8);
      gl2lds16(Wb + (size_t)row * 1024 + k0 + src8 * 8,
               Bs + row * 64 + (tid & 7) * 8);
    }
    __syncthreads();
#pragma unroll
    for (int kk = 0; kk < 2; ++kk) {
      bf16x8 av[4], bv[4];
#pragma unroll
      for (int mt = 0; mt < 4; ++mt)
        av[mt] = *(const bf16x8*)(As + (wr * 64 + mt * 16 + lr) * 64 +
                                  (((kk * 4 + lg) ^ sw) * 8));
#pragma unroll
      for (int nt = 0; nt < 4; ++nt)
        bv[nt] = *(const bf16x8*)(Bs + (wc * 64 + nt * 16 + lr) * 64 +
                                  (((kk * 4 + lg) ^ sw) * 8));
      __builtin_amdgcn_s_setprio(1);
#pragma unroll
      for (int mt = 0; mt < 4; ++mt)
#pragma unroll
        for (int nt = 0; nt < 4; ++nt)
          acc[mt][nt] = mfma16(av[mt], bv[nt], acc[mt][nt]);
      __builtin_amdgcn_s_setprio(0);
    }
  }

  if constexpr (MODE == 0) {
    if (z < 2) {  // Q/K: RoPE + row-major (B,H,S,D)
      unsigned short* Dst = (z == 0) ? Qb : Kb;
#pragma unroll
      for (int mt = 0; mt < 4; ++mt) {
#pragma unroll
        for (int r = 0; r < 4; ++r) {
          const int m = tm * 128 + wr * 64 + mt * 16 + lg * 4 + r;
          const int b = m >> 12, s = m & 4095;
#pragma unroll
          for (int nt = 0; nt < 4; ++nt) {
            const int n = tn * 128 + wc * 64 + nt * 16 + lr;
            const int h = n >> 6, d = n & 63;
            float v = acc[mt][nt][r];
            const float cs = cosT[s * 64 + d];
            const float sn = sinT[s * 64 + d];
            const float pv = acc[mt][nt ^ 2][r];
            v = v * cs + ((nt < 2) ? -pv : pv) * sn;
            Dst[((size_t)(b * 16 + h) * 4096 + s) * 64 + d] = f2bf_n(v);
          }
        }
      }
    } else {  // V: transposed (B,H,D,S), b64 writes (r-consecutive s)
#pragma unroll
      for (int mt = 0; mt < 4; ++mt) {
        const int m0 = tm * 128 + wr * 64 + mt * 16 + lg * 4;
        const int b = m0 >> 12, s0 = m0 & 4095;
#pragma unroll
        for (int nt = 0; nt < 4; ++nt) {
          const int n = tn * 128 + wc * 64 + nt * 16 + lr;
          const int h = n >> 6, d = n & 63;
          u32x2 pw;
          pw[0] = packbf(acc[mt][nt][0], acc[mt][nt][1]);
          pw[1] = packbf(acc[mt][nt][2], acc[mt][nt][3]);
          *(u32x2*)(VT + ((size_t)(b * 16 + h) * 64 + d) * 4096 + s0) = pw;
        }
      }
    }
  } else {
#pragma unroll
    for (int mt = 0; mt < 4; ++mt) {
#pragma unroll
      for (int r = 0; r < 4; ++r) {
        const int m = tm * 128 + wr * 64 + mt * 16 + lg * 4 + r;
#pragma unroll
        for (int nt = 0; nt < 4; ++nt) {
          const int n = tn * 128 + wc * 64 + nt * 16 + lr;
          Out[(size_t)m * 1024 + n] = acc[mt][nt][r];
        }
      }
    }
  }
}

// ---------------- RFA prep: beta/gamma softmax over 128 chunk positions ----------------
__global__ __launch_bounds__(128) void prep_kernel(
    const unsigned short* __restrict__ Kb, const unsigned short* __restrict__ VT,
    const float* __restrict__ mu, const float* __restrict__ phi,
    unsigned short* __restrict__ rfaK, unsigned short* __restrict__ rfaVT) {
  __shared__ float kc[128][65];
  __shared__ float betaS[128], gammaS[128];
  __shared__ float red[8];
  const int tid = threadIdx.x, lane = tid & 63, wid = tid >> 6;
  const int bh = blockIdx.x >> 5, c = blockIdx.x & 31;
  const int h = bh & 15;
  const size_t rowbase = ((size_t)bh * 4096 + c * 128 + tid) * 64;

  float nn = 0.f, dmu = 0.f, dphi = 0.f;
#pragma unroll
  for (int d8 = 0; d8 < 8; ++d8) {
    us8v kv = *(const us8v*)(Kb + rowbase + d8 * 8);
#pragma unroll
    for (int e = 0; e < 8; ++e) {
      const int d = d8 * 8 + e;
      const float kf = bf2f(kv[e]);
      kc[tid][d] = kf;
      nn += kf * kf;
      dmu += kf * mu[h * 64 + d];
      dphi += kf * phi[h * 64 + d];
    }
  }
  const float lb = SCALE_ * dmu - 0.5f * SCALE_ * nn;
  const float lgm = SCALE_ * dphi - 0.5f * SCALE_ * nn;
  float mb = lb, mg = lgm;
  for (int off = 1; off < 64; off <<= 1) {
    mb = fmaxf(mb, __shfl_xor(mb, off));
    mg = fmaxf(mg, __shfl_xor(mg, off));
  }
  if (lane == 0) { red[wid * 2] = mb; red[wid * 2 + 1] = mg; }
  __syncthreads();
  mb = fmaxf(red[0], red[2]);
  mg = fmaxf(red[1], red[3]);
  const float eb = __expf(lb - mb), eg = __expf(lgm - mg);
  float sb = eb, sg = eg;
  for (int off = 1; off < 64; off <<= 1) {
    sb += __shfl_xor(sb, off);
    sg += __shfl_xor(sg, off);
  }
  if (lane == 0) { red[4 + wid * 2] = sb; red[4 + wid * 2 + 1] = sg; }
  betaS[tid] = eb;
  gammaS[tid] = eg;
  __syncthreads();
  sb = red[4] + red[6];
  sg = red[5] + red[7];

  if (tid < 64) {
    float a = 0.f;
    for (int j = 0; j < 128; ++j) a += betaS[j] * kc[j][tid];
    rfaK[((size_t)bh * 32 + c) * 64 + tid] = f2bf(a / sb);
    const unsigned short* vrow = VT + ((size_t)bh * 64 + tid) * 4096 + c * 128;
    float av = 0.f;
#pragma unroll
    for (int j8 = 0; j8 < 16; ++j8) {
      us8v vv = *(const us8v*)(vrow + j8 * 8);
#pragma unroll
      for (int e = 0; e < 8; ++e) av += gammaS[j8 * 8 + e] * bf2f(vv[e]);
    }
    rfaVT[((size_t)bh * 64 + tid) * 32 + c] = f2bf(av / sg);
  }
}

// ---------------- dual-fragment attention tile, shared P buffer ----------------
template <int NCT, bool HASA, bool MASKA, bool MASKB, bool CH>
__device__ __forceinline__ void attn_tile2(
    const unsigned short* __restrict__ klds, const unsigned short* __restrict__ vsrc,
    int t, int w, int qrA, int qrB, int lr, int lg, const bf16x8* qaA,
    const bf16x8* qaB, f32x4* oA, f32x4* oB, float& mA, float& lA, float& mB,
    float& lB, unsigned short (*__restrict__ PtW)[128]) {
  constexpr int VSTRIDE = CH ? 32 : 4096;
  constexpr int NKS = CH ? 1 : 4;
  const int sw = lr & 7;
  // --- V^T fragment loads up front (latency hides under QK^T + softmax) ---
  bf16x8 vf[NKS * 4];
#pragma unroll
  for (int ks = 0; ks < NKS; ++ks)
#pragma unroll
    for (int dt = 0; dt < 4; ++dt)
      vf[ks * 4 + dt] =
          *(const bf16x8*)(vsrc + (size_t)(dt * 16) * VSTRIDE + ks * 32);
  // --- QK^T from LDS K (swizzled read; row&7 == lr&7) ---
  f32x4 stA[NCT], stB[NCT];
#pragma unroll
  for (int ct = 0; ct < NCT; ++ct) {
    bf16x8 b0 = *(const bf16x8*)(klds + (ct * 16 + lr) * 64 + ((lg ^ sw) * 8));
    bf16x8 b1 = *(const bf16x8*)(klds + (ct * 16 + lr) * 64 + (((4 + lg) ^ sw) * 8));
    f32x4 sb_ = {0.f, 0.f, 0.f, 0.f};
    sb_ = mfma16(b0, qaB[0], sb_);
    sb_ = mfma16(b1, qaB[1], sb_);
    f32x4 sa_ = {0.f, 0.f, 0.f, 0.f};
    if constexpr (HASA) {
      sa_ = mfma16(b0, qaA[0], sa_);
      sa_ = mfma16(b1, qaA[1], sa_);
    }
#pragma unroll
    for (int r = 0; r < 4; ++r) {
      const int kidx = ct * 16 + lg * 4 + r;
      float svb = sb_[r] * K_L2E;
      if constexpr (CH) {
        if (kidx >= 4 * w) svb = -1e30f;
      } else if constexpr (MASKB) {
        if (t * 128 + kidx > qrB) svb = -1e30f;
      }
      sb_[r] = svb;
      if constexpr (HASA) {
        float sva = sa_[r] * K_L2E;
        if constexpr (CH) {
          if (kidx >= 4 * w) sva = -1e30f;
        } else if constexpr (MASKA) {
          if (t * 128 + kidx > qrA) sva = -1e30f;
        }
        sa_[r] = sva;
      }
    }
    stB[ct] = sb_;
    if constexpr (HASA) stA[ct] = sa_;
  }
  // --- softmax A and B (independent chains, compiler interleaves) ---
  if constexpr (HASA) {
    f32x4 m4 = stA[0];
#pragma unroll
    for (int ct = 1; ct < NCT; ++ct) m4 = max4(m4, stA[ct]);
    float rm = fmaxf(fmaxf(m4[0], m4[1]), fmaxf(m4[2], m4[3]));
    rm = fmaxf(rm, __shfl_xor(rm, 16));
    rm = fmaxf(rm, __shfl_xor(rm, 32));
    const float mn = fmaxf(mA, rm);
    const float a = exp2_fast(mA - mn);
    f32x4 s4 = {0.f, 0.f, 0.f, 0.f};
#pragma unroll
    for (int ct = 0; ct < NCT; ++ct) {
#pragma unroll
      for (int r = 0; r < 4; ++r) stA[ct][r] = exp2_fast(stA[ct][r] - mn);
      s4 += stA[ct];
    }
    float rs = (s4[0] + s4[1]) + (s4[2] + s4[3]);
    rs += __shfl_xor(rs, 16);
    rs += __shfl_xor(rs, 32);
    lA = lA * a + rs;
    mA = mn;
#pragma unroll
    for (int dt = 0; dt < 4; ++dt)
#pragma unroll
      for (int r = 0; r < 4; ++r) oA[dt][r] *= a;
  }
  {
    f32x4 m4 = stB[0];
#pragma unroll
    for (int ct = 1; ct < NCT; ++ct) m4 = max4(m4, stB[ct]);
    float rm = fmaxf(fmaxf(m4[0], m4[1]), fmaxf(m4[2], m4[3]));
    rm = fmaxf(rm, __shfl_xor(rm, 16));
    rm = fmaxf(rm, __shfl_xor(rm, 32));
    const float mn = fmaxf(mB, rm);
    const float a = exp2_fast(mB - mn);
    f32x4 s4 = {0.f, 0.f, 0.f, 0.f};
#pragma unroll
    for (int ct = 0; ct < NCT; ++ct) {
#pragma unroll
      for (int r = 0; r < 4; ++r) stB[ct][r] = exp2_fast(stB[ct][r] - mn);
      s4 += stB[ct];
    }
    float rs = (s4[0] + s4[1]) + (s4[2] + s4[3]);
    rs += __shfl_xor(rs, 16);
    rs += __shfl_xor(rs, 32);
    lB = lB * a + rs;
    mB = mn;
#pragma unroll
    for (int dt = 0; dt < 4; ++dt)
#pragma unroll
      for (int r = 0; r < 4; ++r) oB[dt][r] *= a;
  }
  // --- PV-A through shared P buffer ---
  if constexpr (HASA) {
#pragma unroll
    for (int ct = 0; ct < NCT; ++ct) {
      u32x2 pw;
      pw[0] = packbf(stA[ct][0], stA[ct][1]);
      pw[1] = packbf(stA[ct][2], stA[ct][3]);
      *(u32x2*)&PtW[lr][((2 * ct + (lg >> 1)) ^ sw) * 8 + (lg & 1) * 4] = pw;
    }
    asm volatile("s_waitcnt lgkmcnt(0)" ::: "memory");
    __builtin_amdgcn_s_setprio(1);
#pragma unroll
    for (int ks = 0; ks < NKS; ++ks) {
      bf16x8 pfA = *(const bf16x8*)&PtW[lr][((ks * 4 + lg) ^ sw) * 8];
#pragma unroll
      for (int dt = 0; dt < 4; ++dt)
        oA[dt] = mfma16(vf[ks * 4 + dt], pfA, oA[dt]);
    }
    __builtin_amdgcn_s_setprio(0);
  }
  // --- PV-B (PB writes queue after PA reads: in-wave DS order -> WAR safe) ---
#pragma unroll
  for (int ct = 0; ct < NCT; ++ct) {
    u32x2 pw;
    pw[0] = packbf(stB[ct][0], stB[ct][1]);
    pw[1] = packbf(stB[ct][2], stB[ct][3]);
    *(u32x2*)&PtW[lr][((2 * ct + (lg >> 1)) ^ sw) * 8 + (lg & 1) * 4] = pw;
  }
  asm volatile("s_waitcnt lgkmcnt(0)" ::: "memory");
  __builtin_amdgcn_s_setprio(1);
#pragma unroll
  for (int ks = 0; ks < NKS; ++ks) {
    bf16x8 pfB = *(const bf16x8*)&PtW[lr][((ks * 4 + lg) ^ sw) * 8];
#pragma unroll
    for (int dt = 0; dt < 4; ++dt)
      oB[dt] = mfma16(vf[ks * 4 + dt], pfB, oB[dt]);
  }
  __builtin_amdgcn_s_setprio(0);
}

// 2048 blocks; wave carries q-fragments {p, 7-p} through ONE k-loop. K tiles
// staged via global_load_lds one tile ahead (double-buffered, swizzled source).
// launch_bounds (256,2): measured-best config (the ~110MB scratch spill is
// benign — off the dependent chain; (256,1) no-spill variant was 10% slower;
// QK^T-setprio and early-pack variants were 25%/10% slower via regalloc
// perturbation).
__global__ __launch_bounds__(256, 2) void attn_kernel(
    const unsigned short* __restrict__ Qb, const unsigned short* __restrict__ Kb,
    const unsigned short* __restrict__ VT, const unsigned short* __restrict__ rfaK,
    const unsigned short* __restrict__ rfaVT, unsigned short* __restrict__ AO) {
  __shared__ unsigned short Klds[2][128][64];  // 32 KB, linear; holds swizzled K
  __shared__ unsigned short Pt[4][16][128];    // 16 KB, shared A/B P per wave
  const int tid = threadIdx.x, lane = tid & 63, wv = tid >> 6;
  const int lr = lane & 15, lg = lane >> 4;
  // XCD-aware swizzle (bijective: 2048 = 8 * 256)
  const int orig = (blockIdx.x & 7) * 256 + (blockIdx.x >> 3);
  const int p = orig & 3, w = (orig >> 2) & 7, bh = orig >> 5;
  const size_t headbase = (size_t)bh * 4096 * 64;
  const int b = bh >> 4, h = bh & 15;

  const int qtA = p, qtB = 7 - p;
  const int qrA = qtA * 64 + wv * 16 + lr;
  const int qrB = qtB * 64 + wv * 16 + lr;

  bf16x8 qaA[2], qaB[2];
  {
    const size_t qoffA = headbase + (size_t)(w * 512 + qrA) * 64;
    qaA[0] = *(const bf16x8*)(Qb + qoffA + lg * 8);
    qaA[1] = *(const bf16x8*)(Qb + qoffA + 32 + lg * 8);
    const size_t qoffB = headbase + (size_t)(w * 512 + qrB) * 64;
    qaB[0] = *(const bf16x8*)(Qb + qoffB + lg * 8);
    qaB[1] = *(const bf16x8*)(Qb + qoffB + 32 + lg * 8);
  }
  f32x4 oA[4], oB[4];
  float mA = -INFINITY, lA = 0.f, mB = -INFINITY, lB = 0.f;
  {
    f32x4 zero = {0.f, 0.f, 0.f, 0.f};
#pragma unroll
    for (int dt = 0; dt < 4; ++dt) { oA[dt] = zero; oB[dt] = zero; }
  }

  unsigned short(*PtW)[128] = Pt[wv];
  const unsigned short* vwin =
      VT + ((size_t)bh * 64 + lr) * 4096 + w * 512 + lg * 8;
  const unsigned short* vchk = rfaVT + ((size_t)bh * 64 + lr) * 32 + lg * 8;
  const unsigned short* kwin = Kb + headbase + (size_t)(w * 512) * 64;
  const unsigned short* kchk = rfaK + (size_t)bh * 32 * 64;

  auto stage_win = [&](const unsigned short* src, int buf) {
#pragma unroll
    for (int i = 0; i < 4; ++i) {
      const int row = wv * 32 + i * 8 + (lane >> 3);
      gl2lds16(src + row * 64 + (((lane & 7) ^ (row & 7)) * 8),
               &Klds[buf][wv * 32 + i * 8][0] + lane * 8);
    }
  };
  auto stage_chk = [&](int buf) {
    const int row = wv * 8 + (lane >> 3);
    gl2lds16(kchk + row * 64 + (((lane & 7) ^ (row & 7)) * 8),
             &Klds[buf][wv * 8][0] + lane * 8);
  };

  const int nktA = (qtA + 2) >> 1;  // 1,1,2,2
  const int nktB = (qtB + 2) >> 1;  // 4,4,3,3  (always > nktA)

  stage_win(kwin, 0);  // prologue: K(0) DMA in flight

  for (int t = 0; t < nktB; ++t) {
    __syncthreads();  // drains K(t) DMA; all waves done reading buf[(t+1)&1]
    if (t + 1 < nktB) {
      stage_win(kwin + (size_t)(t + 1) * 128 * 64, (t + 1) & 1);
    } else if (w > 0) {
      stage_chk((t + 1) & 1);
    }
    const unsigned short* klds = &Klds[t & 1][0][0];
    const unsigned short* vsrc = vwin + t * 128;
    if (t < nktA) {
      if (t == nktA - 1) {
        attn_tile2<8, true, true, false, false>(klds, vsrc, t, w, qrA, qrB, lr,
                                                lg, qaA, qaB, oA, oB, mA, lA, mB,
                                                lB, PtW);
      } else {
        attn_tile2<8, true, false, false, false>(klds, vsrc, t, w, qrA, qrB, lr,
                                                 lg, qaA, qaB, oA, oB, mA, lA,
                                                 mB, lB, PtW);
      }
    } else {
      if (t == nktB - 1) {
        attn_tile2<8, false, false, true, false>(klds, vsrc, t, w, qrA, qrB, lr,
                                                 lg, qaA, qaB, oA, oB, mA, lA,
                                                 mB, lB, PtW);
      } else {
        attn_tile2<8, false, false, false, false>(klds, vsrc, t, w, qrA, qrB, lr,
                                                  lg, qaA, qaB, oA, oB, mA, lA,
                                                  mB, lB, PtW);
      }
    }
  }
  if (w > 0) {
    __syncthreads();  // chunk-K DMA complete
    attn_tile2<2, true, false, false, true>(&Klds[nktB & 1][0][0], vchk, 0, w,
                                            qrA, qrB, lr, lg, qaA, qaB, oA, oB,
                                            mA, lA, mB, lB, PtW);
  }

  // --- epilogues: A then B through the shared P buffer ---
  const int q2 = lane >> 2, db = lane & 3;
  const int sw = lr & 7;
  const int swq = q2 & 7;
  {
    const float inv = 1.0f / lA;
#pragma unroll
    for (int dt = 0; dt < 4; ++dt) {
      u32x2 pw;
      pw[0] = packbf(oA[dt][0] * inv, oA[dt][1] * inv);
      pw[1] = packbf(oA[dt][2] * inv, oA[dt][3] * inv);
      *(u32x2*)&PtW[lr][((2 * dt + (lg >> 1)) ^ sw) * 8 + (lg & 1) * 4] = pw;
    }
    asm volatile("s_waitcnt lgkmcnt(0)" ::: "memory");
    us8v a0 = *(const us8v*)&PtW[q2][((2 * db) ^ swq) * 8];
    us8v a1 = *(const us8v*)&PtW[q2][((2 * db + 1) ^ swq) * 8];
    const int sA = w * 512 + qtA * 64 + wv * 16 + q2;
    unsigned short* dstA = AO + ((size_t)(b * 4096 + sA)) * 1024 + h * 64 + db * 16;
    *(us8v*)dstA = a0;
    *(us8v*)(dstA + 8) = a1;
  }
  {
    const float invb = 1.0f / lB;
#pragma unroll
    for (int dt = 0; dt < 4; ++dt) {
      u32x2 pw;
      pw[0] = packbf(oB[dt][0] * invb, oB[dt][1] * invb);
      pw[1] = packbf(oB[dt][2] * invb, oB[dt][3] * invb);
      *(u32x2*)&PtW[lr][((2 * dt + (lg >> 1)) ^ sw) * 8 + (lg & 1) * 4] = pw;
    }
    asm volatile("s_waitcnt lgkmcnt(0)" ::: "memory");
    us8v b0 = *(const us8v*)&PtW[q2][((2 * db) ^ swq) * 8];
    us8v b1 = *(const us8v*)&PtW[q2][((2 * db + 1) ^ swq) * 8];
    const int sB = w * 512 + qtB * 64 + wv * 16 + q2;
    unsigned short* dstB = AO + ((size_t)(b * 4096 + sB)) * 1024 + h * 64 + db * 16;
    *(us8v*)dstB = b0;
    *(us8v*)(dstB + 8) = b1;
  }
}

// ---------------- host launch ----------------
extern "C" void kernel_launch(void* const* d_in, const int* in_sizes, int n_in,
                              void* d_out, int out_size, void* d_ws, size_t ws_size,
                              hipStream_t stream) {
  const float* hidden = (const float*)d_in[0];
  const float* Wq = (const float*)d_in[1];
  const float* Wk = (const float*)d_in[2];
  const float* Wv = (const float*)d_in[3];
  const float* Wo = (const float*)d_in[4];
  const float* mu = (const float*)d_in[5];
  const float* phi = (const float*)d_in[6];
  const float* cosT = (const float*)d_in[7];
  const float* sinT = (const float*)d_in[8];
  float* out = (float*)d_out;

  char* ws = (char*)d_ws;
  unsigned short* hid_bf = (unsigned short*)(ws);
  unsigned short* wq_bf = (unsigned short*)(ws + 33554432);
  unsigned short* wk_bf = (unsigned short*)(ws + 35651584);
  unsigned short* wv_bf = (unsigned short*)(ws + 37748736);
  unsigned short* wo_bf = (unsigned short*)(ws + 39845888);
  unsigned short* Qb = (unsigned short*)(ws + 41943040);
  unsigned short* Kb = (unsigned short*)(ws + 75497472);
  unsigned short* VT = (unsigned short*)(ws + 109051904);   // (B,H,D,S) bf16
  unsigned short* ao_bf = (unsigned short*)(ws + 142606336);
  unsigned short* rfaK = (unsigned short*)(ws + 176160768);
  unsigned short* rfaVT = (unsigned short*)(ws + 176422912);  // [bh][d][c]

  // hidden + 4 weights in ONE launch: 2097152 + 4*131072 = 2621440 groups
  cvt5_kernel<<<10240, 256, 0, stream>>>(hidden, Wq, Wk, Wv, Wo, hid_bf, wq_bf,
                                         wk_bf, wv_bf, wo_bf);

  gemm_kernel<0><<<dim3(8, 128, 3), 256, 0, stream>>>(
      hid_bf, wq_bf, wk_bf, wv_bf, Qb, Kb, VT, cosT, sinT, nullptr);

  prep_kernel<<<2048, 128, 0, stream>>>(Kb, VT, mu, phi, rfaK, rfaVT);

  attn_kernel<<<2048, 256, 0, stream>>>(Qb, Kb, VT, rfaK, rfaVT, ao_bf);

  gemm_kernel<1><<<dim3(8, 128, 1), 256, 0, stream>>>(
      ao_bf, wo_bf, nullptr, nullptr, nullptr, nullptr, nullptr, nullptr, nullptr,
      out);
}